// Round 11
// baseline (440.658 us; speedup 1.0000x reference)
//
#include <hip/hip_runtime.h>
#include <hip/hip_fp16.h>

// Hankel MPS, round 16: encoder folded into chain_all prologue.
//
// Round-10 post-mortem: prep rewrite bought ~0 — the old scatter reads were
// L2/L3-absorbed (cache overfetch != HBM overfetch). Non-chain pool ~128us:
// enc 53 (sync/latency-bound, ~9us MFMA), prep ~55, gaps ~15. Chain 287us
// is the verified L2-fabric roofline.
//
// Round-16: each chain block needs only its own 32 b's encodings -> compute
// them in chain_all's prologue: per t {stage 32 x rows, L1 (8 waves, W1
// frags hoisted), L2 (4 waves, 32 W2 frags hoisted - read ONCE per block),
// LDS transpose, coalesced fp16 encH write}. Index math transplanted
// verbatim from the verified enc kernel -> absmax must stay bit-identical
// (1.654361e-24). enc_kernel deleted; 3 launches -> 2.
//
// ws: encH 25.17M | HmH 10.49M | HmL 10.49M | w1f 64K | w2f 128K  (46.3 MB)

#define B_ALL 8192
#define TT    12
#define B_T   32     // trajectories per block
#define NBLK  256    // 8192 / 32

typedef short bfrag __attribute__((ext_vector_type(8)));      // 8 bf16
typedef _Float16 hfrag __attribute__((ext_vector_type(8)));   // 8 fp16
typedef float ffrag __attribute__((ext_vector_type(16)));     // 32x32 C/D

#define O_ENC   0ULL
#define O_HMH   25165824ULL
#define O_HML   35651584ULL
#define O_W1F   46137344ULL
#define O_W2F   46202880ULL

__device__ __forceinline__ unsigned short bf16_rne(float f) {
    unsigned int u = __builtin_bit_cast(unsigned int, f);
    unsigned int r = (u + 0x7fffu + ((u >> 16) & 1u)) >> 16;
    return (unsigned short)r;
}
__device__ __forceinline__ float bf16_f32(unsigned short h) {
    unsigned int u = ((unsigned int)h) << 16;
    return __builtin_bit_cast(float, u);
}

// ---------------- prep: coalesced H conversion + W frag-order ----------------
// grid 1288: blocks 0..1279 = one (t,e) H slice each; 1280..1287 = W1/W2.
__global__ __launch_bounds__(256)
void prep_kernel(const float* __restrict__ W1, const float* __restrict__ W2,
                 const float* __restrict__ Hm,
                 __half* __restrict__ w1f, __half* __restrict__ w2f,
                 unsigned short* __restrict__ Hh, unsigned short* __restrict__ Hl)
{
    const int tid = threadIdx.x;
    const int bid = blockIdx.x;
    if (bid < 1280) {
        __shared__ unsigned short hs[4096], ls[4096];
        const int t = bid >> 7, e = bid & 127;
        const float* src = Hm + ((size_t)t * 64 * 128 + e) * 64;   // + p*8192 + r
        const int p  = tid >> 2;
        const int rc = (tid & 3) * 16;
        const int fp = (p >> 4) * 512 + ((p >> 3) & 1) * 256 + (p & 7); // p part of f
        #pragma unroll
        for (int k4 = 0; k4 < 4; ++k4) {
            const int r0 = rc + k4 * 4;
            const float4 v4 = *(const float4*)&src[(size_t)p * 8192 + r0];
            const float vv[4] = {v4.x, v4.y, v4.z, v4.w};
            #pragma unroll
            for (int k = 0; k < 4; ++k) {
                const int r = r0 + k;
                const int f = (r >> 5) * 2048 + (r & 31) * 8 + fp;
                const float val = vv[k];
                const unsigned short hi = bf16_rne(val);
                const unsigned short lo = bf16_rne(val - bf16_f32(hi));
                hs[f] = hi;
                ls[f] = lo;
            }
        }
        __syncthreads();
        const size_t q0 = (size_t)t * 524288 + (size_t)e * 4096 + tid * 16;
        *(uint4*)&Hh[q0]     = *(const uint4*)&hs[tid * 16];
        *(uint4*)&Hh[q0 + 8] = *(const uint4*)&hs[tid * 16 + 8];
        *(uint4*)&Hl[q0]     = *(const uint4*)&ls[tid * 16];
        *(uint4*)&Hl[q0 + 8] = *(const uint4*)&ls[tid * 16 + 8];
    } else {
        const int wb = bid - 1280;
        const long long N_W1 = 32768, N_W2 = 65536;
        for (long long idx = wb * 256 + tid; idx < N_W1 + N_W2; idx += 8 * 256) {
            if (idx < N_W1) {
                const int w = (int)idx;
                const int jn = w >> 11, ks = (w >> 9) & 3, half = (w >> 8) & 1;
                const int jl = (w >> 3) & 31, jj = w & 7;
                const int j = jn * 32 + jl, d = ks * 16 + half * 8 + jj;
                w1f[w] = __float2half(W1[j * 64 + d]);
            } else {
                const int w = (int)(idx - N_W1);
                const int en = w >> 14, ks2g = (w >> 9) & 31, half = (w >> 8) & 1;
                const int el = (w >> 3) & 31, jj = w & 7;
                const int e = en * 32 + el, j = ks2g * 16 + half * 8 + jj;
                w2f[w] = __float2half(W2[e * 512 + j]);
            }
        }
    }
}

// ---------------- chain_all: enc prologue + init + 10 steps + final ----------------
// 256 blocks x 512 thr (1 block/CU). Block owns b0..b0+31.
//
// enc phase LDS (temporally disjoint from chain overlay):
//   x_s     @ 0     : [32][68] f32        = 8704
//   h_s     @ 8704  : [32][514] fp16      = 32896  (stride 514: conflict-free)
//   enc_tmp @ 41600 : [128][33] f32       = 16896  -> ends 58496
// chain overlay (r12/r15, verified):
//   vsum  @ 0      : [64][33] f32   = 8448
//   enc_s @ 8448   : [128][33] f32  = 16896
//   scr   @ 25344  : stride-66 float4 combine
//   hl_s  @ 25344  : [64][129] f32  (final)
//   red   @ 58368  : [16][33] f32   (final)
__global__ __launch_bounds__(512, 1)
void chain_all(const unsigned short* __restrict__ HmH,
               const unsigned short* __restrict__ HmL,
               const float* __restrict__ x,
               const float* __restrict__ b1, const float* __restrict__ b2,
               const __half* __restrict__ w1f, const __half* __restrict__ w2f,
               __half* __restrict__ encH,
               const float* __restrict__ Hf,
               const float* __restrict__ HL,
               float* __restrict__ out)
{
    __shared__ __align__(16) unsigned char smem[60480];
    // chain overlay
    float* vsum  = (float*)smem;
    float* enc_s = (float*)(smem + 8448);
    float* scr   = (float*)(smem + 25344);
    float* hl_s  = (float*)(smem + 25344);
    float* red   = (float*)(smem + 58368);
    // enc overlay
    float*  x_s     = (float*)smem;
    __half* h_s     = (__half*)(smem + 8704);
    float*  enc_tmp = (float*)(smem + 41600);

    const int tid  = threadIdx.x;
    const int b0   = blockIdx.x * B_T;
    const int lane = tid & 63;
    const int wv   = tid >> 6;
    const int l32  = lane & 31;
    const int half = lane >> 5;
    const int eq   = wv >> 1;      // 0..3  (e-quarter, chain)
    const int rh   = wv & 1;       // 0..1  (r-half, chain)

    // ======== enc prologue: encH for own 32 b, all 12 t ========
    {
        // hoisted W1 fragments (all 8 waves): jn = wv*2 + nf
        const int jn0 = wv * 2;
        hfrag w1a[2][4];
        float b1j[2];
        #pragma unroll
        for (int nf = 0; nf < 2; ++nf) {
            b1j[nf] = b1[(jn0 + nf) * 32 + l32];
            #pragma unroll
            for (int ks = 0; ks < 4; ++ks)
                w1a[nf][ks] = *(const hfrag*)(w1f + ((jn0 + nf) * 4 + ks) * 512
                                              + half * 256 + l32 * 8);
        }
        // hoisted W2 fragments (waves 0..3): en = wv, read ONCE per block
        const int en = wv;
        hfrag w2b[32];
        float b2v = 0.0f;
        if (wv < 4) {
            b2v = b2[en * 32 + l32];
            #pragma unroll
            for (int k2 = 0; k2 < 32; ++k2)
                w2b[k2] = *(const hfrag*)(w2f + (en * 32 + k2) * 512
                                          + half * 256 + l32 * 8);
        }

        #pragma unroll 1
        for (int t = 0; t < TT; ++t) {
            // stage x: 32 rows x 64 f32
            {
                const int row = tid >> 4, c4 = (tid & 15) * 4;
                *(float4*)&x_s[row * 68 + c4] =
                    *(const float4*)&x[((size_t)(b0 + row) * 12 + t) * 64 + c4];
            }
            __syncthreads();
            // layer 1 (all 8 waves)
            hfrag xa[4];
            #pragma unroll
            for (int ks = 0; ks < 4; ++ks) {
                const float* src = &x_s[l32 * 68 + ks * 16 + half * 8];
                const float4 a = *(const float4*)src;
                const float4 b = *(const float4*)(src + 4);
                hfrag v;
                v[0] = (_Float16)a.x; v[1] = (_Float16)a.y;
                v[2] = (_Float16)a.z; v[3] = (_Float16)a.w;
                v[4] = (_Float16)b.x; v[5] = (_Float16)b.y;
                v[6] = (_Float16)b.z; v[7] = (_Float16)b.w;
                xa[ks] = v;
            }
            #pragma unroll
            for (int nf = 0; nf < 2; ++nf) {
                ffrag acc = 0.0f;
                #pragma unroll
                for (int ks = 0; ks < 4; ++ks)
                    acc = __builtin_amdgcn_mfma_f32_32x32x16_f16(xa[ks], w1a[nf][ks],
                                                                 acc, 0, 0, 0);
                #pragma unroll
                for (int i2 = 0; i2 < 16; ++i2) {
                    const int m_row = (i2 & 3) + 8 * (i2 >> 2) + 4 * half;
                    const float v = fmaxf(acc[i2] + b1j[nf], 0.0f);
                    h_s[m_row * 514 + (jn0 + nf) * 32 + l32] = __float2half(v);
                }
            }
            __syncthreads();
            // layer 2 (waves 0..3)
            if (wv < 4) {
                ffrag c2 = 0.0f;
                #pragma unroll
                for (int k2 = 0; k2 < 32; ++k2) {
                    const hfrag a = *(const hfrag*)&h_s[l32 * 514 + k2 * 16 + half * 8];
                    c2 = __builtin_amdgcn_mfma_f32_32x32x16_f16(a, w2b[k2], c2, 0, 0, 0);
                }
                #pragma unroll
                for (int i2 = 0; i2 < 16; ++i2) {
                    const int m_row = (i2 & 3) + 8 * (i2 >> 2) + 4 * half;
                    enc_tmp[(en * 32 + l32) * 33 + m_row] =
                        fmaxf(c2[i2] + b2v, 0.0f);
                }
            }
            __syncthreads();
            // pack -> encH (coalesced 16B/thread)
            {
                const int bl = tid >> 4, eo = (tid & 15) * 8;
                __half hv[8];
                #pragma unroll
                for (int j = 0; j < 8; ++j)
                    hv[j] = __float2half(enc_tmp[(eo + j) * 33 + bl]);
                *(uint4*)&encH[((size_t)(b0 + bl) * 12 + t) * 128 + eo] =
                    *(const uint4*)hv;
            }
            __syncthreads();
        }
    }

    // enc staging for chain phases: [128 e][32 b] f32 from encH
    const int sbL = tid >> 4;            // 0..31 (b-local)
    const int seo = (tid & 15) * 8;      // 0..120 (e-offset)
    #define STAGE_ENC(T)                                                      \
    {                                                                         \
        const __half* er_ = encH + ((size_t)(b0 + sbL) * 12 + (T)) * 128 + seo;\
        uint4 u = *(const uint4*)er_;                                         \
        const __half* hp_ = (const __half*)&u;                                \
        _Pragma("unroll")                                                     \
        for (int j = 0; j < 8; ++j)                                           \
            enc_s[(seo + j) * 33 + sbL] = __half2float(hp_[j]);               \
    }

    // ---- init: v0[p][b] = sum_e enc(b,0,e) * Hf[e][p] ----
    {
        STAGE_ENC(0);
        __syncthreads();
        const int bI = tid & 31, pg = tid >> 5;   // pg 0..15
        const int p0 = pg * 4;
        float a0 = 0, a1 = 0, a2 = 0, a3 = 0;
        for (int e = 0; e < 128; ++e) {
            const float ev = enc_s[e * 33 + bI];
            const float4 h = *(const float4*)&Hf[e * 64 + p0];  // half-wave-uniform
            a0 += ev * h.x; a1 += ev * h.y; a2 += ev * h.z; a3 += ev * h.w;
        }
        vsum[(p0 + 0) * 33 + bI] = a0;
        vsum[(p0 + 1) * 33 + bI] = a1;
        vsum[(p0 + 2) * 33 + bI] = a2;
        vsum[(p0 + 3) * 33 + bI] = a3;
        __syncthreads();
    }

    // ---- chain: 10 steps, all in-block (r12 verified) ----
    const unsigned short* Hsh = HmH;
    const unsigned short* Hsl = HmL;
    const int lanoff = rh * 2048 + half * 256 + l32 * 8;

    #pragma unroll 1
    for (int t = 1; t <= 10; ++t) {
        STAGE_ENC(t);

        // B-frags: v hi/lo split from vsum (stable since last sync)
        bfrag vbh[4], vbl[4];
        #pragma unroll
        for (int s = 0; s < 4; ++s) {
            const int p0 = s * 16 + half * 8;
            bfrag hb, lb;
            #pragma unroll
            for (int j = 0; j < 8; ++j) {
                const float f = vsum[(p0 + j) * 33 + l32];
                const unsigned short hi = bf16_rne(f);
                const unsigned short lo = bf16_rne(f - bf16_f32(hi));
                hb[j] = (short)hi;
                lb[j] = (short)lo;
            }
            vbh[s] = hb;
            vbl[s] = lb;
        }
        __syncthreads();   // enc_s staged; vsum reads complete

        // e-loop: this wave's 32-e quarter, software-pipelined (prefetch e+1)
        const unsigned short* hp = Hsh + (size_t)(eq * 32) * 4096 + lanoff;
        const unsigned short* lp = Hsl + (size_t)(eq * 32) * 4096 + lanoff;
        bfrag cah[4], cal[4];
        #pragma unroll
        for (int s = 0; s < 4; ++s) {
            cah[s] = *(const bfrag*)(hp + s * 512);
            cal[s] = *(const bfrag*)(lp + s * 512);
        }
        ffrag z = 0.0f;
        ffrag vn = 0.0f;
        #pragma unroll 2
        for (int e = 0; e < 32; ++e) {
            hp += 4096; lp += 4096;
            // prefetch next e (last iter reads <=8KB past slice: allocated ws)
            bfrag nah[4], nal[4];
            #pragma unroll
            for (int s = 0; s < 4; ++s) {
                nah[s] = *(const bfrag*)(hp + s * 512);
                nal[s] = *(const bfrag*)(lp + s * 512);
            }
            const float ev = enc_s[(eq * 32 + e) * 33 + l32];
            ffrag w = z;
            #pragma unroll
            for (int s = 0; s < 4; ++s) {
                w = __builtin_amdgcn_mfma_f32_32x32x16_bf16(cah[s], vbh[s], w, 0, 0, 0);
                w = __builtin_amdgcn_mfma_f32_32x32x16_bf16(cah[s], vbl[s], w, 0, 0, 0);
                w = __builtin_amdgcn_mfma_f32_32x32x16_bf16(cal[s], vbh[s], w, 0, 0, 0);
            }
            vn += w * ev;
            #pragma unroll
            for (int s = 0; s < 4; ++s) { cah[s] = nah[s]; cal[s] = nal[s]; }
        }
        __syncthreads();   // e-loop LDS reads done; scr region free

        // cross-eq combine in LDS (stride 66 float4)
        float4* sc4 = (float4*)scr;
        if (eq != 0) {
            const int slot = (eq - 1) * 2 + rh;
            #pragma unroll
            for (int q = 0; q < 4; ++q) {
                float4 f4 = {vn[q * 4 + 0], vn[q * 4 + 1],
                             vn[q * 4 + 2], vn[q * 4 + 3]};
                sc4[(slot * 4 + q) * 66 + lane] = f4;
            }
        }
        __syncthreads();
        if (eq == 0) {
            #pragma unroll
            for (int g = 1; g < 4; ++g) {
                const int slot = (g - 1) * 2 + rh;
                #pragma unroll
                for (int q = 0; q < 4; ++q) {
                    const float4 f4 = sc4[(slot * 4 + q) * 66 + lane];
                    vn[q * 4 + 0] += f4.x; vn[q * 4 + 1] += f4.y;
                    vn[q * 4 + 2] += f4.z; vn[q * 4 + 3] += f4.w;
                }
            }
            #pragma unroll
            for (int i = 0; i < 16; ++i) {
                const int r = rh * 32 + (i & 3) + 8 * (i >> 2) + 4 * half;
                vsum[r * 33 + l32] = vn[i];
            }
        }
        __syncthreads();   // vsum ready for next step

        Hsh += 524288;
        Hsl += 524288;
    }

    // ---- final: out[b] = sum_p v[p][b] * (sum_e enc(b,11,e) * HL[p][e]) ----
    {
        STAGE_ENC(11);
        #pragma unroll
        for (int i = 0; i < 16; ++i) {
            const int idx = i * 512 + tid;       // 8192 floats of HL [p][e]
            hl_s[(idx >> 7) * 129 + (idx & 127)] = HL[idx];
        }
        __syncthreads();
        const int bI = tid & 31, pg = tid >> 5;
        const int p0 = pg * 4;
        float s = 0.0f;
        #pragma unroll
        for (int i = 0; i < 4; ++i) {
            float L = 0.0f;
            #pragma unroll 16
            for (int e = 0; e < 128; ++e)
                L += enc_s[e * 33 + bI] * hl_s[(p0 + i) * 129 + e];
            s += vsum[(p0 + i) * 33 + bI] * L;
        }
        red[pg * 33 + bI] = s;
        __syncthreads();
        if (tid < 32) {
            float acc = 0.0f;
            #pragma unroll
            for (int g = 0; g < 16; ++g)
                acc += red[g * 33 + tid];
            out[b0 + tid] = acc;
        }
    }
    #undef STAGE_ENC
}

extern "C" void kernel_launch(void* const* d_in, const int* in_sizes, int n_in,
                              void* d_out, int out_size, void* d_ws, size_t ws_size,
                              hipStream_t stream) {
    const float* x  = (const float*)d_in[0];
    const float* W1 = (const float*)d_in[1];
    const float* b1 = (const float*)d_in[2];
    const float* W2 = (const float*)d_in[3];
    const float* b2 = (const float*)d_in[4];
    const float* Hf = (const float*)d_in[5];
    const float* Hm = (const float*)d_in[6];
    const float* HL = (const float*)d_in[7];
    float* out = (float*)d_out;
    (void)in_sizes; (void)n_in; (void)out_size; (void)ws_size;

    char* ws = (char*)d_ws;
    __half* encH        = (__half*)(ws + O_ENC);
    unsigned short* HmH = (unsigned short*)(ws + O_HMH);
    unsigned short* HmL = (unsigned short*)(ws + O_HML);
    __half* w1f         = (__half*)(ws + O_W1F);
    __half* w2f         = (__half*)(ws + O_W2F);

    prep_kernel<<<dim3(1288), dim3(256), 0, stream>>>(W1, W2, Hm, w1f, w2f, HmH, HmL);
    chain_all<<<dim3(NBLK), dim3(512), 0, stream>>>(HmH, HmL, x, b1, b2, w1f, w2f,
                                                    encH, Hf, HL, out);
}